// Round 2
// baseline (737.030 us; speedup 1.0000x reference)
//
#include <hip/hip_runtime.h>

// Problem constants (match reference)
#define NB   4096
#define NK   8
#define NH   64
#define NW   64
#define NS   50
#define NHID 64
#define NCTX 71   // 9*K - 1

// z slice per b: K*H*W = 32768 floats = 128 KiB; packed = 4 KiB (512 u64)

// Packed-bit layout (from float4 + 4 ballots):
//   cell = (k<<12)|(i<<6)|j  (flat index within a b-slice)
//   group g = cell>>8 (256 cells), comp = cell&3, lane = (cell>>2)&63
//   word = (g<<2)|comp, bit = lane
__device__ __forceinline__ int getbit(const unsigned long long* bits, int cell) {
    int word = ((cell >> 8) << 2) | (cell & 3);
    int bit  = (cell >> 2) & 63;
    return (int)((bits[word] >> bit) & 1ull);
}

__global__ __launch_bounds__(256, 4)
void local_energy_kernel(const float* __restrict__ z,
                         const float* __restrict__ W1,   // (71,64)
                         const float* __restrict__ b1,   // (64)
                         const float* __restrict__ W2,   // (64)
                         const float* __restrict__ b2,   // (1)
                         const int*   __restrict__ b_idx,
                         const int*   __restrict__ i_idx,
                         const int*   __restrict__ j_idx,
                         float*       __restrict__ out)
{
    __shared__ unsigned long long bits[512];   // 4 KiB packed slice
    __shared__ float blocksum[4];

    const int tid  = threadIdx.x;
    const int lane = tid & 63;
    const int wave = tid >> 6;
    const int b    = blockIdx.x;

    // ---- phase 1: coalesced load of z[b] slice, ballot-pack into LDS ----
    // (runs BEFORE weight loads so staging regs and W1c don't overlap ->
    //  peak VGPR pressure stays under the launch_bounds(256,4) 128-cap)
    const float4* src = (const float4*)(z + (size_t)b * (NK * NH * NW));
    // 8192 float4 / 256 threads = 32 iterations, 4-deep load staging
    for (int outer = 0; outer < 8; ++outer) {
        float4 v[4];
        #pragma unroll
        for (int q = 0; q < 4; ++q)
            v[q] = src[(outer * 4 + q) * 256 + tid];
        #pragma unroll
        for (int q = 0; q < 4; ++q) {
            int iter = outer * 4 + q;
            unsigned long long m0 = __ballot(v[q].x > 0.5f);
            unsigned long long m1 = __ballot(v[q].y > 0.5f);
            unsigned long long m2 = __ballot(v[q].z > 0.5f);
            unsigned long long m3 = __ballot(v[q].w > 0.5f);
            if (lane == 0) {
                int g = (iter << 2) | wave;    // cells [g*256, g*256+256)
                bits[(g << 2) | 0] = m0;
                bits[(g << 2) | 1] = m1;
                bits[(g << 2) | 2] = m2;
                bits[(g << 2) | 3] = m3;
            }
        }
    }
    __syncthreads();

    // ---- per-lane weights: W1 column for hid = lane (registers) ----
    float W1c[NCTX];
    #pragma unroll
    for (int t = 0; t < NCTX; ++t) W1c[t] = W1[t * NHID + lane];
    const float b1v = b1[lane];
    const float W2v = W2[lane];
    const float b2v = b2[0];

    // ---- phase 2: one wave per sample (s = wave, wave+4, ...) ----
    float miss = 0.0f;
    for (int s = wave; s < NS; s += 4) {
        const int bb = b_idx[s];
        const int ii = i_idx[s];
        const int jj = j_idx[s];

        // ctx bit u = p*8 + k, p = (di+1)*3 + (dj+1). Lane extracts bit u=lane.
        int u  = lane;
        int p  = u >> 3, k = u & 7;
        int di = p / 3, dj = p - di * 3;
        int ni = (ii + di - 1) & (NH - 1);
        int nj = (jj + dj - 1) & (NW - 1);
        int cell = (k << 12) | (ni << 6) | nj;
        unsigned long long lo = __ballot(getbit(bits, cell) != 0);

        // bits 64..71 come from lanes 0..7 (p = 8: di=+1, dj=+1, k = lane)
        int k2  = lane & 7;
        int ni2 = (ii + 1) & (NH - 1);
        int nj2 = (jj + 1) & (NW - 1);
        int cell2 = (k2 << 12) | (ni2 << 6) | nj2;
        int bv2 = (lane < 8) ? getbit(bits, cell2) : 0;
        unsigned long long hi = __ballot(bv2 != 0) & 0xffull;

        // delete bit 'drop' from 72-bit (hi:lo) -> 71-bit (mhi:mlo)
        const int drop = 32 + bb;          // in [32,40) -> always inside lo
        unsigned long long mlo = (lo & ((1ull << drop) - 1ull))
                               | ((lo >> (drop + 1)) << drop)
                               | ((hi & 1ull) << 63);
        unsigned int mhi = (unsigned int)(hi >> 1);   // 7 bits

        // h[lane] = relu(b1 + sum of selected W1 rows)  (mask is wave-uniform)
        float h0 = b1v, h1 = 0.0f, h2 = 0.0f, h3 = 0.0f;
        #pragma unroll
        for (int t = 0; t < 64; t += 4) {
            h0 += ((mlo >> (t + 0)) & 1ull) ? W1c[t + 0] : 0.0f;
            h1 += ((mlo >> (t + 1)) & 1ull) ? W1c[t + 1] : 0.0f;
            h2 += ((mlo >> (t + 2)) & 1ull) ? W1c[t + 2] : 0.0f;
            h3 += ((mlo >> (t + 3)) & 1ull) ? W1c[t + 3] : 0.0f;
        }
        #pragma unroll
        for (int t = 0; t < 7; ++t)
            h0 += ((mhi >> t) & 1u) ? W1c[64 + t] : 0.0f;
        float h = fmaxf((h0 + h1) + (h2 + h3), 0.0f);

        // logit = sum_lane h*W2 + b2  (64-lane butterfly reduce)
        float c = h * W2v;
        #pragma unroll
        for (int off = 32; off >= 1; off >>= 1)
            c += __shfl_xor(c, off, 64);
        float logit = c + b2v;

        int pred = (logit > 0.0f) ? 1 : 0;
        int cellT = (bb << 12) | (ii << 6) | jj;
        int targ  = getbit(bits, cellT);
        if (lane == 0) miss += (float)(pred != targ);
    }

    if (lane == 0) blocksum[wave] = miss;
    __syncthreads();
    if (tid == 0) {
        float tot = (blocksum[0] + blocksum[1]) + (blocksum[2] + blocksum[3]);
        atomicAdd(out, tot * (1.0f / (float)(NB * NS)));
    }
}

extern "C" void kernel_launch(void* const* d_in, const int* in_sizes, int n_in,
                              void* d_out, int out_size, void* d_ws, size_t ws_size,
                              hipStream_t stream) {
    const float* z    = (const float*)d_in[0];
    const float* W1   = (const float*)d_in[1];
    const float* b1   = (const float*)d_in[2];
    const float* W2   = (const float*)d_in[3];
    const float* b2   = (const float*)d_in[4];
    const int*   b_i  = (const int*)d_in[5];
    const int*   i_i  = (const int*)d_in[6];
    const int*   j_i  = (const int*)d_in[7];
    float* out = (float*)d_out;

    // d_out is poisoned before every call; zero it (async, capture-safe)
    hipMemsetAsync(out, 0, sizeof(float), stream);

    local_energy_kernel<<<NB, 256, 0, stream>>>(z, W1, b1, W2, b2, b_i, i_i, j_i, out);
}

// Round 5
// 714.004 us; speedup vs baseline: 1.0322x; 1.0322x over previous
//
#include <hip/hip_runtime.h>

// Problem constants (match reference)
#define NB   4096
#define NK   8
#define NH   64
#define NW   64
#define NS   50
#define NHID 64
#define NCTX 71   // 9*K - 1

typedef float f32x4 __attribute__((ext_vector_type(4)));

// Packed-bit layout (from float4 + 4 ballots):
//   cell = (k<<12)|(i<<6)|j  (flat index within a b-slice)
//   word = ((cell>>8)<<2)|(cell&3), bit = (cell>>2)&63
__device__ __forceinline__ int getbit(const unsigned long long* bits, int cell) {
    int word = ((cell >> 8) << 2) | (cell & 3);
    int bit  = (cell >> 2) & 63;
    return (int)((bits[word] >> bit) & 1ull);
}

__global__ __launch_bounds__(256, 4)
void local_energy_kernel(const float* __restrict__ z,
                         const float* __restrict__ W1,   // (71,64)
                         const float* __restrict__ b1,   // (64)
                         const float* __restrict__ W2,   // (64)
                         const float* __restrict__ b2,   // (1)
                         const int*   __restrict__ b_idx,
                         const int*   __restrict__ i_idx,
                         const int*   __restrict__ j_idx,
                         float*       __restrict__ partials)  // d_ws, NB floats
{
    __shared__ unsigned long long bits[512];   // 4 KiB packed slice
    __shared__ int   sidx[3][NS];              // b/i/j sample indices
    __shared__ float blocksum[4];

    const int tid  = threadIdx.x;
    const int lane = tid & 63;
    const int wave = tid >> 6;
    const int b    = blockIdx.x;

    // ---- phase 0: stage the 150 sample indices into LDS ----
    if (tid < 3 * NS) {
        int a = tid / NS, r = tid - a * NS;
        const int* p = (a == 0) ? b_idx : (a == 1) ? i_idx : j_idx;
        sidx[a][r] = p[r];
    }

    // ---- phase 1: coalesced nontemporal load of z[b], ballot-pack to LDS ----
    const f32x4* src = (const f32x4*)(z + (size_t)b * (NK * NH * NW));
    for (int outer = 0; outer < 8; ++outer) {
        f32x4 v[4];
        #pragma unroll
        for (int q = 0; q < 4; ++q)
            v[q] = __builtin_nontemporal_load(&src[(outer * 4 + q) * 256 + tid]);
        #pragma unroll
        for (int q = 0; q < 4; ++q) {
            int iter = outer * 4 + q;
            unsigned long long m0 = __ballot(v[q][0] > 0.5f);
            unsigned long long m1 = __ballot(v[q][1] > 0.5f);
            unsigned long long m2 = __ballot(v[q][2] > 0.5f);
            unsigned long long m3 = __ballot(v[q][3] > 0.5f);
            if (lane == 0) {
                int g = (iter << 2) | wave;    // cells [g*256, g*256+256)
                bits[(g << 2) | 0] = m0;
                bits[(g << 2) | 1] = m1;
                bits[(g << 2) | 2] = m2;
                bits[(g << 2) | 3] = m3;
            }
        }
    }
    __syncthreads();

    // ---- per-lane weights: W1 column for hid = lane (after phase 1, so
    //      streaming regs and W1c never coexist -> fits 128-VGPR cap) ----
    float W1c[NCTX];
    #pragma unroll
    for (int t = 0; t < NCTX; ++t) W1c[t] = W1[t * NHID + lane];
    const float b1v = b1[lane];
    const float W2v = W2[lane];
    const float b2v = b2[0];

    // per-lane ctx-position constants (loop-invariant): bit u = p*8 + k
    const int p  = lane >> 3;          // 0..7 (position 8 handled via hi path)
    const int kk = lane & 7;
    const int di = p / 3, dj = p - di * 3;

    // ---- phase 2: one wave per sample (s = wave, wave+4, ...) ----
    float miss = 0.0f;
    for (int s = wave; s < NS; s += 4) {
        const int bb = sidx[0][s];
        const int ii = sidx[1][s];
        const int jj = sidx[2][s];

        int ni = (ii + di - 1) & (NH - 1);
        int nj = (jj + dj - 1) & (NW - 1);
        int cell = (kk << 12) | (ni << 6) | nj;
        unsigned long long lo = __ballot(getbit(bits, cell) != 0);

        // bits 64..71 from lanes 0..7 (pos 8: di=+1, dj=+1, k=lane)
        int ni2 = (ii + 1) & (NH - 1);
        int nj2 = (jj + 1) & (NW - 1);
        int cell2 = ((lane & 7) << 12) | (ni2 << 6) | nj2;
        int bv2 = (lane < 8) ? getbit(bits, cell2) : 0;
        unsigned long long hi = __ballot(bv2 != 0) & 0xffull;

        // delete bit 'drop' from 72-bit (hi:lo) -> 71-bit (mhi:mlo)
        const int drop = 32 + bb;          // in [32,40) -> always inside lo
        unsigned long long mlo = (lo & ((1ull << drop) - 1ull))
                               | ((lo >> (drop + 1)) << drop)
                               | ((hi & 1ull) << 63);
        unsigned int mhi = (unsigned int)(hi >> 1);   // 7 bits

        // h[lane] = relu(b1 + sum of selected W1 rows); mask wave-uniform
        float h0 = b1v, h1 = 0.0f, h2 = 0.0f, h3 = 0.0f;
        #pragma unroll
        for (int t = 0; t < 64; t += 4) {
            h0 += ((mlo >> (t + 0)) & 1ull) ? W1c[t + 0] : 0.0f;
            h1 += ((mlo >> (t + 1)) & 1ull) ? W1c[t + 1] : 0.0f;
            h2 += ((mlo >> (t + 2)) & 1ull) ? W1c[t + 2] : 0.0f;
            h3 += ((mlo >> (t + 3)) & 1ull) ? W1c[t + 3] : 0.0f;
        }
        #pragma unroll
        for (int t = 0; t < 7; ++t)
            h0 += ((mhi >> t) & 1u) ? W1c[64 + t] : 0.0f;
        float h = fmaxf((h0 + h1) + (h2 + h3), 0.0f);

        // logit = sum_lane h*W2 + b2  (64-lane butterfly reduce)
        float c = h * W2v;
        #pragma unroll
        for (int off = 32; off >= 1; off >>= 1)
            c += __shfl_xor(c, off, 64);
        float logit = c + b2v;

        int pred = (logit > 0.0f) ? 1 : 0;
        int cellT = (bb << 12) | (ii << 6) | jj;
        int targ  = getbit(bits, cellT);
        if (lane == 0) miss += (float)(pred != targ);
    }

    if (lane == 0) blocksum[wave] = miss;
    __syncthreads();
    if (tid == 0)
        partials[b] = (blocksum[0] + blocksum[1]) + (blocksum[2] + blocksum[3]);
}

// Sum NB per-block mismatch counts -> scalar mean
__global__ __launch_bounds__(256)
void reduce_kernel(const float* __restrict__ partials, float* __restrict__ out)
{
    __shared__ float wsum[4];
    const int tid  = threadIdx.x;
    const int lane = tid & 63;
    const int wave = tid >> 6;

    float s = 0.0f;
    #pragma unroll
    for (int q = 0; q < NB / 256; ++q)
        s += partials[q * 256 + tid];
    #pragma unroll
    for (int off = 32; off >= 1; off >>= 1)
        s += __shfl_xor(s, off, 64);
    if (lane == 0) wsum[wave] = s;
    __syncthreads();
    if (tid == 0)
        out[0] = ((wsum[0] + wsum[1]) + (wsum[2] + wsum[3]))
                 * (1.0f / (float)(NB * NS));
}

extern "C" void kernel_launch(void* const* d_in, const int* in_sizes, int n_in,
                              void* d_out, int out_size, void* d_ws, size_t ws_size,
                              hipStream_t stream) {
    const float* z    = (const float*)d_in[0];
    const float* W1   = (const float*)d_in[1];
    const float* b1   = (const float*)d_in[2];
    const float* W2   = (const float*)d_in[3];
    const float* b2   = (const float*)d_in[4];
    const int*   b_i  = (const int*)d_in[5];
    const int*   i_i  = (const int*)d_in[6];
    const int*   j_i  = (const int*)d_in[7];
    float* out      = (float*)d_out;
    float* partials = (float*)d_ws;   // NB floats

    local_energy_kernel<<<NB, 256, 0, stream>>>(z, W1, b1, W2, b2, b_i, i_i, j_i, partials);
    reduce_kernel<<<1, 256, 0, stream>>>(partials, out);
}